// Round 3
// baseline (1098.106 us; speedup 1.0000x reference)
//
#include <hip/hip_runtime.h>
#include <math.h>

// BWNet scan, R2b: 16 scan blocks, 2 barriers/step, no acquire-invalidate.
// Cross-block data moves via relaxed agent-scope (sc1) atomics only, so
// read-only data (keys/weights) stays cached across the whole scan.
// Blocks 16..255 zero unit_logits rows [steps..8192) concurrently.

typedef float v4f __attribute__((ext_vector_type(4)));
typedef float v2f __attribute__((ext_vector_type(2)));

#define N_ENT 8192
#define EMB   256
#define KD    32
#define ARD   1024
#define UT    233
#define NSCAN 16
#define NZBLK 240
#define NBLK  256
#define CPB   512   // key columns per scan block
#define ARB   64    // ar-slice length per scan block

// float-index offsets into d_ws
#define WS_KEYS 0         // 32*8192, k-major
#define WS_C0   262144    // 256: b_a0 + relu(W_fe@um + b_fe)
#define WS_I0P  262400    // 16*256 i0 partials
#define WS_PSUM 266496    // 16
#define WS_PMAX 266512    // 16
// int-index offsets
#define WS_PIDX 266528    // 16
#define WS_CTR  266560    // monotonic barrier counter
#define WS_FLAG 266592    // release flag (separate 128B line)

struct Params {
  const float *um, *emask, *enc, *arin, *W_fe, *b_fe, *W_k, *b_k,
              *W_a0, *b_a0, *W_a1, *b_a1, *W_f, *b_f, *W_i0, *b_i0,
              *W_i1, *b_i1, *W_o, *b_o, *ln_g, *ln_b, *W_a3, *b_a3;
  const int* ct;
  float* out;
  float* wsf;
  int*   wsi;
};

__device__ __forceinline__ void st_af(float* p, float v) {
  __hip_atomic_store(p, v, __ATOMIC_RELAXED, __HIP_MEMORY_SCOPE_AGENT);
}
__device__ __forceinline__ void st_ai(int* p, int v) {
  __hip_atomic_store(p, v, __ATOMIC_RELAXED, __HIP_MEMORY_SCOPE_AGENT);
}
__device__ __forceinline__ float alf(float* p) {
  return __hip_atomic_load(p, __ATOMIC_RELAXED, __HIP_MEMORY_SCOPE_AGENT);
}
__device__ __forceinline__ int ali(int* p) {
  return __hip_atomic_load(p, __ATOMIC_RELAXED, __HIP_MEMORY_SCOPE_AGENT);
}

// Barrier over the NSCAN scan blocks: monotonic counter + release flag.
// __syncthreads drains vmcnt so each block's sc1 publishes are at the
// coherence point before its arrival increment. Last arriver writes flag.
__device__ __forceinline__ void gbar(int* ctr, int* flag, int epoch) {
  __syncthreads();
  if (threadIdx.x == 0) {
    int old = __hip_atomic_fetch_add(ctr, 1, __ATOMIC_RELAXED, __HIP_MEMORY_SCOPE_AGENT);
    if (old == NSCAN * epoch - 1) {
      st_ai(flag, epoch);
    } else {
      int guard = 0;
      while (ali(flag) < epoch) {
        __builtin_amdgcn_s_sleep(1);
        if (++guard > (1 << 22)) break;  // failsafe: never hang
      }
    }
  }
  __syncthreads();
}

// ---------------- init: keys GEMM (k-major), c0, barrier state ----------------
__global__ __launch_bounds__(256) void k_init(Params p) {
  __shared__ float enc_s[32 * 260];
  __shared__ float um_s[UT];
  const int tid = threadIdx.x, bid = blockIdx.x;
  float* keys = p.wsf + WS_KEYS;

  if (bid == 0 && tid < UT) um_s[tid] = p.um[tid];
  if (bid == 3 && tid == 0) { p.wsi[WS_CTR] = 0; p.wsi[WS_FLAG] = 0; }

  const int j0 = bid * 32;
  #pragma unroll
  for (int i = 0; i < 8; ++i) {
    int idx = i * 256 + tid;
    int row = idx >> 6, c4 = idx & 63;
    v4f v = *(const v4f*)(p.enc + (size_t)(j0 + row) * EMB + c4 * 4);
    *(v4f*)&enc_s[row * 260 + c4 * 4] = v;
  }
  __syncthreads();
  {
    const int jl = tid >> 3, kg = tid & 7;
    float acc[4];
    #pragma unroll
    for (int kk = 0; kk < 4; ++kk) acc[kk] = p.b_k[kg * 4 + kk];
    for (int e4 = 0; e4 < 64; ++e4) {
      v4f x = *(const v4f*)&enc_s[jl * 260 + e4 * 4];
      #pragma unroll
      for (int kk = 0; kk < 4; ++kk) {
        v4f w = *(const v4f*)(p.W_k + (size_t)(kg * 4 + kk) * EMB + e4 * 4);
        acc[kk] += x.x * w.x + x.y * w.y + x.z * w.z + x.w * w.w;
      }
    }
    const int j = j0 + jl;
    #pragma unroll
    for (int kk = 0; kk < 4; ++kk) keys[(size_t)(kg * 4 + kk) * N_ENT + j] = acc[kk];
  }
  if (bid == 0) {  // c0 = relu(W_fe@um + b_fe) + b_a0
    float a = p.b_fe[tid];
    const float* wr = p.W_fe + (size_t)tid * UT;
    for (int u = 0; u < UT; ++u) a += wr[u] * um_s[u];
    p.wsf[WS_C0 + tid] = fmaxf(a, 0.f) + p.b_a0[tid];
  }
}

// ---------------- main: scan (blocks 0..15) + zeroing (16..255) ----------------
__global__ __launch_bounds__(256, 1) void k_scan(Params p) {
  const int tid = threadIdx.x, bid = blockIdx.x;
  int ctv = p.ct[0];
  const int steps = ctv < 0 ? 0 : (ctv > 64 ? 64 : ctv);
  const size_t NN = (size_t)N_ENT * N_ENT;

  if (bid >= NSCAN) {  // -------- zero role --------
    v4f z = (v4f){0.f, 0.f, 0.f, 0.f};
    v4f* o4 = (v4f*)p.out;
    const size_t tot = NN / 4;
    for (size_t i = (size_t)steps * (N_ENT / 4) + (size_t)(bid - NSCAN) * 256 + tid;
         i < tot; i += (size_t)NZBLK * 256)
      __builtin_nontemporal_store(z, o4 + i);
    return;
  }

  // -------- scan role --------
  __shared__ float kslice[KD * CPB];   // 64KB: this block's 512 key columns
  __shared__ float wa3s[ARB * 33];     // W_a3 rows [64b,64b+64), padded
  __shared__ float arsl[ARB];          // own ar slice (replicated update)
  __shared__ float ri0_s[8 * 33];
  __shared__ float x_i1[32], q_s[32], h_s[32], qnf[32];
  __shared__ float garr[128], fog[32], rem[32], og[32], cent[32];
  __shared__ float b_a1s[32], gb_s[128], b_a3sl[ARB], lng_s[32], lnb_s[32];
  __shared__ float reds[4], rmaxs[4];
  __shared__ int ridxs[4];
  __shared__ unsigned pickedbits[N_ENT / 32];  // 1KB local mask-updates
  __shared__ float ssum_s;
  __shared__ int pick_s, active_s, done_s, hit_s, nanfree_s;
  __shared__ float lds_pad[1200];  // push LDS > 80KB: force 1 block/CU

  float* keys = p.wsf + WS_KEYS;
  float* i0p  = p.wsf + WS_I0P;
  float* psum = p.wsf + WS_PSUM;
  float* pmax = p.wsf + WS_PMAX;
  int* pidx = p.wsi + WS_PIDX;
  int* ctrp = p.wsi + WS_CTR;
  int* flgp = p.wsi + WS_FLAG;

  // ---- preamble ----
  for (int i4 = tid; i4 < KD * (CPB / 4); i4 += 256) {  // kslice (v4f)
    int k = i4 >> 7, c4 = i4 & 127;
    v4f v = *(const v4f*)(keys + (size_t)k * N_ENT + (bid << 9) + c4 * 4);
    *(v4f*)&kslice[k * CPB + c4 * 4] = v;
  }
  for (int i4 = tid; i4 < ARB * 8; i4 += 256) {  // W_a3 slice
    int r = i4 >> 3, c4 = i4 & 7;
    v4f v = *(const v4f*)(p.W_a3 + (size_t)(bid * ARB + r) * KD + c4 * 4);
    float* d = &wa3s[r * 33 + c4 * 4];
    d[0] = v.x; d[1] = v.y; d[2] = v.z; d[3] = v.w;
  }
  if (tid < ARB) { arsl[tid] = p.arin[bid * ARB + tid]; b_a3sl[tid] = p.b_a3[bid * ARB + tid]; }
  if (tid < 32) {
    b_a1s[tid] = p.b_a1[tid]; lng_s[tid] = p.ln_g[tid]; lnb_s[tid] = p.ln_b[tid];
    q_s[tid] = 0.f; h_s[tid] = 0.f; qnf[tid] = 0.f; x_i1[tid] = 0.f;
  }
  if (tid < 128) {
    const int g = tid >> 5, r = tid & 31;
    const float* bg = (g == 0) ? p.b_f : (g == 1) ? p.b_i0 : (g == 2) ? p.b_i1 : p.b_o;
    gb_s[tid] = bg[r];
  }
  pickedbits[tid] = 0u;
  if (tid == 0) { active_s = 1; done_s = 0; hit_s = 0; nanfree_s = 1; lds_pad[0] = 0.f; }
  const float c0r = p.wsf[WS_C0 + tid];

  v4f w0r[16];  // W_a0 row tid, cols [64b,64b+64)
  { const float* s = p.W_a0 + (size_t)tid * ARD + bid * ARB;
    #pragma unroll
    for (int i = 0; i < 16; ++i) w0r[i] = ((const v4f*)s)[i]; }
  v4f w1[8];    // W_a1 row tid>>3, col-group (tid&7)*32
  { const float* s = p.W_a1 + (size_t)(tid >> 3) * EMB + (tid & 7) * 32;
    #pragma unroll
    for (int i = 0; i < 8; ++i) w1[i] = ((const v4f*)s)[i]; }
  v4f wg[8];    // LSTM gate row tid>>1, half tid&1
  { const int rowg = tid >> 1, g = rowg >> 5, r = rowg & 31, half = tid & 1;
    const float* W = (g == 0) ? p.W_f : (g == 1) ? p.W_i0 : (g == 2) ? p.W_i1 : p.W_o;
    const float* s = W + r * 64 + half * 32;
    #pragma unroll
    for (int i = 0; i < 8; ++i) wg[i] = ((const v4f*)s)[i]; }
  __syncthreads();

  // pre-loop: publish i0 partial from initial ar slice
  {
    float part = 0.f;
    #pragma unroll
    for (int i = 0; i < 16; ++i) {
      part += w0r[i].x * arsl[4 * i] + w0r[i].y * arsl[4 * i + 1] +
              w0r[i].z * arsl[4 * i + 2] + w0r[i].w * arsl[4 * i + 3];
    }
    st_af(&i0p[bid * 256 + tid], part);
  }
  gbar(ctrp, flgp, 1);

  float v0 = 0.f, v1 = 0.f;
  for (int t = 0; t < steps; ++t) {
    // ==== Region B: gather i0, LSTM chain -> qn, sweep own 512 cols ====
    {
      float acc = c0r;
      #pragma unroll
      for (int b2 = 0; b2 < NSCAN; ++b2) acc += alf(&i0p[b2 * 256 + tid]);
      ri0_s[(tid >> 5) * 33 + (tid & 31)] = fmaxf(acc, 0.f);
    }
    __syncthreads();
    {  // i1 = relu(W_a1 @ ri0 + b_a1)
      const int r = tid >> 3, s8 = tid & 7;
      float p1 = 0.f;
      #pragma unroll
      for (int i = 0; i < 8; ++i) {
        const float* xx = &ri0_s[s8 * 33 + 4 * i];
        p1 += w1[i].x * xx[0] + w1[i].y * xx[1] + w1[i].z * xx[2] + w1[i].w * xx[3];
      }
      #pragma unroll
      for (int m = 4; m; m >>= 1) p1 += __shfl_xor(p1, m);
      if (s8 == 0) x_i1[r] = fmaxf(p1 + b_a1s[r], 0.f);
    }
    __syncthreads();
    {  // 4 LSTM gate matvecs
      const int rowg = tid >> 1, g = rowg >> 5, half = tid & 1;
      const float* xsrc = half ? q_s : x_i1;
      float pg = 0.f;
      #pragma unroll
      for (int i = 0; i < 8; ++i)
        pg += wg[i].x * xsrc[4 * i] + wg[i].y * xsrc[4 * i + 1] +
              wg[i].z * xsrc[4 * i + 2] + wg[i].w * xsrc[4 * i + 3];
      pg += __shfl_xor(pg, 1);
      if (!half) {
        pg += gb_s[rowg];
        garr[rowg] = (g == 2) ? tanhf(pg) : 1.f / (1.f + __expf(-pg));
      }
    }
    __syncthreads();
    {  // 3 layernorms, one per wave
      const int w = tid >> 6, k = tid & 63;
      if (w < 3 && k < 32) {
        float a = (w == 0) ? garr[k] : (w == 1) ? garr[32 + k] * garr[64 + k] : garr[96 + k];
        float s = a;
        #pragma unroll
        for (int m = 16; m; m >>= 1) s += __shfl_xor(s, m);
        const float mean = s * (1.f / 32.f);
        const float d = a - mean;
        float vv = d * d;
        #pragma unroll
        for (int m = 16; m; m >>= 1) vv += __shfl_xor(vv, m);
        vv *= (1.f / 32.f);
        const float y = d * rsqrtf(vv + 1e-5f) * lng_s[k] + lnb_s[k];
        if (w == 0) fog[k] = y; else if (w == 1) rem[k] = y; else og[k] = y;
      }
    }
    __syncthreads();
    if (tid < 32) {
      const float nh = rem[tid] + fog[tid] * h_s[tid];
      const float qv = tanhf(nh) * og[tid];
      qnf[tid] = qv;
      if (active_s) { h_s[tid] = nh; q_s[tid] = qv; }
    }
    __syncthreads();
    {  // sweep: 2 adjacent cols per thread via ds_read_b64
      float d0 = 0.f, d1 = 0.f;
      #pragma unroll
      for (int k = 0; k < 32; ++k) {
        const v2f kk = *(const v2f*)&kslice[k * CPB + 2 * tid];
        const float qk = qnf[k];
        d0 += qk * kk.x; d1 += qk * kk.y;
      }
      const float s0 = 1.f / (1.f + __expf(-d0));
      const float s1 = 1.f / (1.f + __expf(-d1));
      v0 = __expf(__logf(s0) * 1.25f);  // sig^(1/0.8)
      v1 = __expf(__logf(s1) * 1.25f);
      float sv = v0 + v1;
      float mv; int mi;
      const int gi0 = (bid << 9) + 2 * tid;
      if (v1 > v0) { mv = v1; mi = gi0 + 1; } else { mv = v0; mi = gi0; }
      #pragma unroll
      for (int m = 32; m; m >>= 1) {
        sv += __shfl_xor(sv, m);
        const float ov = __shfl_xor(mv, m);
        const int oi = __shfl_xor(mi, m);
        if (ov > mv || (ov == mv && oi < mi)) { mv = ov; mi = oi; }
      }
      const int wv = tid >> 6;
      if ((tid & 63) == 0) { reds[wv] = sv; rmaxs[wv] = mv; ridxs[wv] = mi; }
      __syncthreads();
      if (tid == 0) {
        float S = ((reds[0] + reds[1]) + reds[2]) + reds[3];
        float M = rmaxs[0]; int I = ridxs[0];
        #pragma unroll
        for (int i2 = 1; i2 < 4; ++i2)
          if (rmaxs[i2] > M || (rmaxs[i2] == M && ridxs[i2] < I)) { M = rmaxs[i2]; I = ridxs[i2]; }
        st_af(&psum[bid], S); st_af(&pmax[bid], M); st_ai(&pidx[bid], I);
      }
    }
    gbar(ctrp, flgp, 2 * t + 2);

    // ==== Region A: global reduce, row write, state update, next i0 partial ====
    if (tid < 64) {
      const int b2 = tid & 15;
      float s = alf(&psum[b2]), m = alf(&pmax[b2]);
      int ii = ali(&pidx[b2]);
      #pragma unroll
      for (int mm = 1; mm <= 8; mm <<= 1) {
        s += __shfl_xor(s, mm);
        const float om = __shfl_xor(m, mm);
        const int oi = __shfl_xor(ii, mm);
        if (om > m || (om == m && oi < ii)) { m = om; ii = oi; }
      }
      if (tid == 0) { ssum_s = s; pick_s = ii; }
    }
    __syncthreads();
    const int pick = pick_s;
    const float ssum = ssum_s;
    const int act = active_s;
    const int valid = (ssum != 0.f) ? 1 : 0;
    {  // row write
      v2f r2;
      if (act && valid) { r2.x = v0 / ssum; r2.y = v1 / ssum; }
      else { r2.x = 0.f; r2.y = 0.f; }
      __builtin_nontemporal_store(r2, (v2f*)(p.out + (size_t)t * N_ENT + (bid << 9) + 2 * tid));
    }
    if (tid < 32) {  // centered selection
      const float kv = keys[(size_t)tid * N_ENT + pick];  // plain load, stays cached
      float mn = kv;
      #pragma unroll
      for (int mm = 16; mm; mm >>= 1) mn += __shfl_xor(mn, mm);
      mn *= (1.f / 32.f);
      const float cv = kv - mn;
      cent[tid] = cv;
      const unsigned long long bb = __ballot(cv != cv);
      if (tid == 0) nanfree_s = (bb == 0ULL) ? 1 : 0;
    }
    __syncthreads();
    if (tid == 0) {
      const int notpicked = ((pickedbits[pick >> 5] >> (pick & 31)) & 1u) == 0u;
      const int mask_ok = (p.emask[pick] != 0.f) && notpicked;
      const int hit = act && valid && mask_ok;
      hit_s = hit;
      if (hit) {
        pickedbits[pick >> 5] |= (1u << (pick & 31));
        if (!nanfree_s) done_s = 1;
      }
      active_s = done_s ? 0 : 1;
    }
    __syncthreads();
    if (tid < ARB) {  // ar slice update (block-local)
      float dl = b_a3sl[tid];
      #pragma unroll
      for (int c = 0; c < 32; ++c) dl += wa3s[tid * 33 + c] * cent[c];
      if (hit_s && nanfree_s) arsl[tid] += fmaxf(dl, 0.f);
    }
    __syncthreads();
    if (t + 1 < steps) {
      float part = 0.f;
      #pragma unroll
      for (int i = 0; i < 16; ++i)
        part += w0r[i].x * arsl[4 * i] + w0r[i].y * arsl[4 * i + 1] +
                w0r[i].z * arsl[4 * i + 2] + w0r[i].w * arsl[4 * i + 3];
      st_af(&i0p[bid * 256 + tid], part);
      gbar(ctrp, flgp, 2 * t + 3);
    }
  }

  // ==== epilogue ====
  if (tid < ARB) p.out[NN + N_ENT + bid * ARB + tid] = arsl[tid];
  if (bid == 0) {
    for (int i = tid; i < N_ENT; i += 256)
      p.out[NN + i] = ((pickedbits[i >> 5] >> (i & 31)) & 1u) ? 1.f : 0.f;
  }
}

extern "C" void kernel_launch(void* const* d_in, const int* in_sizes, int n_in,
                              void* d_out, int out_size, void* d_ws, size_t ws_size,
                              hipStream_t stream) {
  (void)in_sizes; (void)n_in; (void)out_size; (void)ws_size;
  Params p;
  p.um    = (const float*)d_in[0];
  p.emask = (const float*)d_in[1];
  p.enc   = (const float*)d_in[2];
  p.arin  = (const float*)d_in[3];
  p.W_fe  = (const float*)d_in[4];
  p.b_fe  = (const float*)d_in[5];
  p.W_k   = (const float*)d_in[6];
  p.b_k   = (const float*)d_in[7];
  p.W_a0  = (const float*)d_in[8];
  p.b_a0  = (const float*)d_in[9];
  p.W_a1  = (const float*)d_in[10];
  p.b_a1  = (const float*)d_in[11];
  p.W_f   = (const float*)d_in[12];
  p.b_f   = (const float*)d_in[13];
  p.W_i0  = (const float*)d_in[14];
  p.b_i0  = (const float*)d_in[15];
  p.W_i1  = (const float*)d_in[16];
  p.b_i1  = (const float*)d_in[17];
  p.W_o   = (const float*)d_in[18];
  p.b_o   = (const float*)d_in[19];
  p.ln_g  = (const float*)d_in[20];
  p.ln_b  = (const float*)d_in[21];
  p.W_a3  = (const float*)d_in[22];
  p.b_a3  = (const float*)d_in[23];
  p.ct    = (const int*)d_in[24];
  p.out   = (float*)d_out;
  p.wsf   = (float*)d_ws;
  p.wsi   = (int*)d_ws;

  hipLaunchKernelGGL(k_init, dim3(NBLK), dim3(256), 0, stream, p);
  hipLaunchKernelGGL(k_scan, dim3(NBLK), dim3(256), 0, stream, p);
}